// Round 7
// baseline (200.416 us; speedup 1.0000x reference)
//
#include <hip/hip_runtime.h>
#include <hip/hip_bf16.h>

typedef __hip_bfloat16 bf16;
typedef unsigned short ushort8v __attribute__((ext_vector_type(8)));
typedef short  s16x4  __attribute__((ext_vector_type(4)));
typedef short  bf16x8 __attribute__((ext_vector_type(8)));   // 8 bf16 (4 VGPRs)
typedef float  f32x4  __attribute__((ext_vector_type(4)));

#define HW 4096
#define IMG_W 64

__device__ __forceinline__ float bfbits2f(unsigned short u) {
    return __uint_as_float(((unsigned int)u) << 16);
}
__device__ __forceinline__ short f2bs(float f) {
    bf16 h = __float2bfloat16(f);
    return *reinterpret_cast<short*>(&h);
}

// async global->LDS, 16B per lane (wave-uniform LDS base + lane*16 scatter).
__device__ __forceinline__ void gl_lds16(const void* g, void* s) {
    __builtin_amdgcn_global_load_lds(
        (const __attribute__((address_space(1))) unsigned int*)g,
        (__attribute__((address_space(3))) unsigned int*)s, 16, 0, 0);
}

// ---------------------------------------------------------------------------
// pack_input: concat(gar,cond) fp32 [512][4096] -> inp_t bf16 chunked
// [cc=16][pix=4096][32ch] (conv1 DMA layout) AND gar_t bf16 pixel-major
// [4096 px][256 ch] (warp_combine gather layout: a 32-lane channel-group
// reads 512 B contiguous -> 4x128B cache lines per gather instead of
// 16x64B with the chunked layout).
// ---------------------------------------------------------------------------
__device__ void pack_input_dev(const float* __restrict__ gar,
                               const float* __restrict__ cond,
                               short* __restrict__ outp,
                               short* __restrict__ gart, int bx2, float* tile)
{
    int bx = bx2 & 127;                // px tile (128)
    int by = bx2 >> 7;                 // ch tile (16) == cc chunk
    int tx = threadIdx.x & 31;
    int ty = threadIdx.x >> 5;
#pragma unroll
    for (int i = 0; i < 4; ++i) {
        int c = by * 32 + ty + i * 8;
        const float* src = (c < 256) ? (gar + (size_t)c * HW)
                                     : (cond + (size_t)(c - 256) * HW);
        tile[(ty + i * 8) * 33 + tx] = src[bx * 32 + tx];
    }
    __syncthreads();
#pragma unroll
    for (int i = 0; i < 4; ++i) {
        int p = bx * 32 + ty + i * 8;
        short v = f2bs(tile[tx * 33 + ty + i * 8]);
        outp[((size_t)by * 4096 + p) * 32 + tx] = v;
        if (by < 8)                    // gar channels only (block-uniform)
            gart[(size_t)p * 256 + by * 32 + tx] = v;
    }
}

// ---------------------------------------------------------------------------
// pack_w: W fp32 [G][CREAL][CIN][3][3] -> bf16 blocks.
// COAL=false (conv3-4): [g][nt][cc][tap 9][q 4][oc BN][8 ic]   (old layout)
// COAL=true  (conv1-2): [g][nt][cc][tap 9][oc BN][q 4][8 ic]   -> a wave's
//   64-lane weight-fragment load is one contiguous span.
// BLKB = 9*4*BN*16 bytes either way.
// ---------------------------------------------------------------------------
template<int CIN, int CREAL, int BN, int NT, bool COAL>
__device__ void pack_w_dev(const float* __restrict__ wgt, char* __restrict__ wp,
                           int bx, short* sT)
{
    constexpr int NCC  = CIN / 32;
    constexpr int BLKB = 9 * 4 * BN * 16;

    const int t  = threadIdx.x;
    const int cc = bx % NCC;
    const int nt = (bx / NCC) % NT;
    const int g  = bx / (NT * NCC);

    for (int i = t; i < BLKB / 8; i += 256)
        reinterpret_cast<s16x4*>(sT)[i] = s16x4{0, 0, 0, 0};
    __syncthreads();

    int ocmax = CREAL - nt * BN; if (ocmax > BN) ocmax = BN;
    const size_t base = ((size_t)(g * CREAL + nt * BN) * CIN + cc * 32) * 9;
    for (int i = t; i < ocmax * 288; i += 256) {
        int oc = i / 288;
        int r  = i % 288;                      // ic*9 + tap
        int ic = r / 9, tap = r % 9;
        size_t idx;
        if (COAL) idx = (size_t)(((tap * BN + oc) * 4 + (ic >> 3)) * 8 + (ic & 7));
        else      idx = (size_t)(((tap * 4 + (ic >> 3)) * BN + oc) * 8 + (ic & 7));
        sT[idx] = f2bs(wgt[base + (size_t)oc * CIN * 9 + r]);
    }
    __syncthreads();

    const s16x4* src = reinterpret_cast<const s16x4*>(sT);
    s16x4* dst = reinterpret_cast<s16x4*>(wp + (size_t)bx * BLKB);
    for (int i = t; i < BLKB / 8; i += 256)
        dst[i] = src[i];
}

// All packing in one launch (block-range dispatch; branch is block-uniform).
__global__ __launch_bounds__(256)
void pack_all(const float* __restrict__ gar, const float* __restrict__ cond,
              const float* __restrict__ W1, const float* __restrict__ W2,
              const float* __restrict__ W3, const float* __restrict__ W4,
              short* inp_t, short* gar_t,
              char* W1p, char* W2p, char* W3p, char* W4p)
{
    __shared__ __align__(16) short sbuf[9 * 4 * 64 * 8];   // 36864 B
    int bx = blockIdx.x;
    if (bx < 256)      pack_w_dev<512, 128, 64, 2, true >(W1, W1p, bx,       sbuf);
    else if (bx < 288) pack_w_dev<128,  64, 64, 1, true >(W2, W2p, bx - 256, sbuf);
    else if (bx < 304) pack_w_dev< 64,  32, 32, 1, false>(W3, W3p, bx - 288, sbuf);
    else if (bx < 312) pack_w_dev< 32,  18, 32, 1, false>(W4, W4p, bx - 304, sbuf);
    else pack_input_dev(gar, cond, inp_t, gar_t, bx - 312, (float*)sbuf);
}

// ---------------------------------------------------------------------------
// Implicit-GEMM 3x3 SAME conv, bf16 MFMA 16x16x32, conflict-free LDS.
// (old template — still used for conv3/conv4; input layout [pix][ICP])
// ---------------------------------------------------------------------------
template<int ICP, int CREAL, int BN, int ROWS, int OF, int NT, int NW, int PIPE,
         bool PIXMAJ_OUT, bool LEAKY, bool OUT_F32>
__global__ __launch_bounds__(NW * 64, 2)
void conv_mfma(const short* __restrict__ inp, const char* __restrict__ wp,
               const float* __restrict__ bias, void* __restrict__ outv)
{
    constexpr int NCC  = ICP / 32;
    constexpr int HALO = ROWS + 2;
    constexpr int NPT  = 4096 / (ROWS * 64);
    constexpr int BLKB = 9 * 4 * BN * 16;
    constexpr int RNDS = BLKB / 1024;
    constexpr int NBUF = (PIPE && NCC > 1) ? 2 : 1;
    constexpr int SMAX = (HALO + NW - 1) / NW;

    __shared__ __align__(16) short sA[HALO][4][68][8];
    __shared__ __align__(16) char  sBraw[NBUF][BLKB];

    const int b  = blockIdx.x;
    const int g  = b & 7;                     // XCD swizzle: group per XCD
    const int r_ = b >> 3;
    const int pt = r_ % NPT;
    const int nt = r_ / NPT;
    const int r0 = pt * ROWS;

    const int t    = threadIdx.x;
    const int wave = t >> 6, lane = t & 63;
    const int l15  = lane & 15, quad = lane >> 4;

    int row_l, ocw;
    if (NW == 8) {
        if (ROWS == 4) { row_l = wave >> 1; ocw = (wave & 1) * (BN / 2); }
        else           { row_l = wave >> 2; ocw = (wave & 3) * (BN / 4); }
    } else {
        row_l = (ROWS == 4) ? wave : (wave & 1);
        ocw   = (ROWS == 4) ? 0 : (wave >> 1) * (BN / 2);
    }

    const size_t gpix = (ICP == 512) ? 0 : ((size_t)g * 4096);
    const char*  wb   = wp + (size_t)((g * NT + nt) * NCC) * BLKB;

    // sA staging: thread -> (col, row-slice); rows j = r2, r2+NW, ...
    const int acol = t & 63;
    const int r2   = t >> 6;

    bf16x8 pre[SMAX][4];

    auto stageA_load = [&](int cc) {
#pragma unroll
        for (int s = 0; s < SMAX; ++s) {
            int j = r2 + s * NW;
            if (j < HALO) {
                int gy = r0 - 1 + j;
                if (gy >= 0 && gy < 64) {
                    const short* sp = inp + ((gpix + gy * 64 + acol) * ICP + cc * 32);
#pragma unroll
                    for (int q = 0; q < 4; ++q)
                        pre[s][q] = *reinterpret_cast<const bf16x8*>(sp + q * 8);
                } else {
#pragma unroll
                    for (int q = 0; q < 4; ++q)
                        pre[s][q] = bf16x8{0, 0, 0, 0, 0, 0, 0, 0};
                }
            }
        }
    };
    auto stageA_write = [&]() {
#pragma unroll
        for (int s = 0; s < SMAX; ++s) {
            int j = r2 + s * NW;
            if (j < HALO) {
#pragma unroll
                for (int q = 0; q < 4; ++q)
                    *reinterpret_cast<bf16x8*>(&sA[j][q][acol + 1][0]) = pre[s][q];
            }
        }
    };
    auto stageB = [&](int cc) {
        const char* wsrc = wb + (size_t)cc * BLKB;
        char* sbb = (char*)sBraw[(NBUF == 2) ? (cc & 1) : 0];
        for (int r = wave; r < RNDS; r += NW)
            gl_lds16(wsrc + r * 1024 + lane * 16, sbb + r * 1024);
    };

    f32x4 acc[OF][4];
#pragma unroll
    for (int o = 0; o < OF; ++o)
#pragma unroll
        for (int p = 0; p < 4; ++p)
#pragma unroll
            for (int r = 0; r < 4; ++r) acc[o][p][r] = 0.f;

    // zero the x-pad column units (col index 0 and 65) once
    if (t < HALO * 8) {
        int row = t >> 3, q = (t >> 1) & 3, cp = (t & 1) ? 65 : 0;
        *reinterpret_cast<bf16x8*>(&sA[row][q][cp][0]) =
            bf16x8{0, 0, 0, 0, 0, 0, 0, 0};
    }

    // prologue: stage phase 0
    stageB(0);
    stageA_load(0);
    stageA_write();

    for (int cc = 0; cc < NCC; ++cc) {
        __syncthreads();               // sB(cc) drained, sA(cc) visible
        if (cc + 1 < NCC) {
            if (PIPE) stageB(cc + 1);  // dbuf: DMA into alternate buffer now
            stageA_load(cc + 1);       // global -> regs, no LDS touch
        }
        const bf16x8* sBv = reinterpret_cast<const bf16x8*>(
            sBraw[(NBUF == 2) ? (cc & 1) : 0]);

#pragma unroll
        for (int dy = 0; dy < 3; ++dy) {
#pragma unroll
            for (int dx = 0; dx < 3; ++dx) {
                bf16x8 pF[4];
#pragma unroll
                for (int p = 0; p < 4; ++p)
                    pF[p] = *reinterpret_cast<const bf16x8*>(
                        &sA[row_l + dy][quad][p * 16 + l15 + dx][0]);
                bf16x8 wF[OF];
#pragma unroll
                for (int o = 0; o < OF; ++o)
                    wF[o] = sBv[((dy * 3 + dx) * 4 + quad) * BN + ocw + o * 16 + l15];
#pragma unroll
                for (int o = 0; o < OF; ++o)
#pragma unroll
                    for (int p = 0; p < 4; ++p)
                        acc[o][p] = __builtin_amdgcn_mfma_f32_16x16x32_bf16(
                            wF[o], pF[p], acc[o][p], 0, 0, 0);
            }
        }
        __syncthreads();               // all reads of sA(cc)/sB(cc) done
        if (cc + 1 < NCC) {
            if (!PIPE) stageB(cc + 1); // single-buf: DMA into the freed buffer
            stageA_write();
        }
    }

    // ---- epilogue. C/D: m(oc) = quad*4+reg, n(pixel) = l15.
    const int prow = r0 + row_l;
#pragma unroll
    for (int o = 0; o < OF; ++o)
#pragma unroll
        for (int reg = 0; reg < 4; ++reg) {
            const int ocl = ocw + o * 16 + quad * 4 + reg;
            const int ocg = nt * BN + ocl;
            if (ocg < CREAL) {
                const float bv = bias[g * CREAL + ocg];
                if (PIXMAJ_OUT) {
                    short* outp = (short*)outv;
                    const size_t pixbase = ((size_t)g * 4096 + prow * 64);
#pragma unroll
                    for (int p = 0; p < 4; ++p) {
                        float v = acc[o][p][reg] + bv;
                        if (LEAKY) v = v >= 0.f ? v : 0.1f * v;
                        outp[(pixbase + p * 16 + l15) * (NT * BN) + ocg] = f2bs(v);
                    }
                } else if (OUT_F32) {
                    float* outp = (float*)outv;
                    const size_t base = ((size_t)(g * CREAL + ocg)) * HW + prow * IMG_W;
#pragma unroll
                    for (int p = 0; p < 4; ++p) {
                        float v = acc[o][p][reg] + bv;
                        if (LEAKY) v = v >= 0.f ? v : 0.1f * v;
                        outp[base + p * 16 + l15] = v;
                    }
                } else {
                    short* outp = (short*)outv;
                    const size_t base = ((size_t)(g * CREAL + ocg)) * HW + prow * IMG_W;
#pragma unroll
                    for (int p = 0; p < 4; ++p) {
                        float v = acc[o][p][reg] + bv;
                        if (LEAKY) v = v >= 0.f ? v : 0.1f * v;
                        outp[base + p * 16 + l15] = f2bs(v);
                    }
                }
            }
        }
}

// ---------------------------------------------------------------------------
// conv1_p2: dual-stream register pipeline, full-K (round-6 verified, 49.6us).
// CHANGE this round: epilogue writes hid1 CHUNKED [cc4][32768 pix][32] so
// conv2_p2 can DMA-stage it exactly like conv1 stages inp_t.
// ---------------------------------------------------------------------------
__global__ __launch_bounds__(512, 2)
void conv1_p2(const short* __restrict__ inp, const char* __restrict__ wp,
              const float* __restrict__ bias, short* __restrict__ outp)
{
    __shared__ __align__(16) short sA[2][4][66][4][8];   // 33792 B

    const int b  = blockIdx.x;
    const int g  = b & 7;                     // XCD swizzle: group per XCD
    const int pt = b >> 3;                    // 0..31
    const int r0 = pt * 2;

    const int t    = threadIdx.x;
    const int wave = t >> 6, lane = t & 63;
    const int l15  = lane & 15, quad = lane >> 4;

    const int row_l = wave & 1;               // px row (0-1)
    const int ocq   = wave >> 1;              // oc quarter (0-3)
    const int ntw   = ocq >> 1;               // W1p nt half
    const int ocw64 = (ocq & 1) * 32;         // oc base within nt

    // W1p layout [g][nt][cc 16][tap 9][oc 64][q 4][ic 8]
    const short* wb    = (const short*)wp + (size_t)(g * 2 + ntw) * 16 * 18432;
    const short* wlane = wb + ((size_t)(ocw64 + l15) * 4 + quad) * 8;

    // staging: wave w -> halo row (w>>1), column half (w&1): 2 x 1KB DMA
    auto stageDMA = [&](int cc, int buf) {
        const int row = wave >> 1;
        const int gy  = r0 - 1 + row;
        if (gy >= 0 && gy < 64) {
            const short* src = inp + ((size_t)cc * 4096 + (size_t)gy * 64) * 32
                                   + (size_t)lane * 8;
            const int c4 = (wave & 1) * 2;
            gl_lds16(src + c4 * 512,       &sA[buf][row][1 + c4 * 16][0][0]);
            gl_lds16(src + (c4 + 1) * 512, &sA[buf][row][1 + (c4 + 1) * 16][0][0]);
        }
    };

    f32x4 acc[2][4];
#pragma unroll
    for (int o = 0; o < 2; ++o)
#pragma unroll
        for (int f = 0; f < 4; ++f)
#pragma unroll
            for (int r = 0; r < 4; ++r) acc[o][f][r] = 0.f;

    // prologue: DMA(0) into buf0, zero x-pads (both bufs) + OOB rows
    stageDMA(0, 0);
    if (t < 64) {
        int buf = t >> 5, row = (t >> 3) & 3, q = (t >> 1) & 3;
        int col = (t & 1) ? 65 : 0;
        *reinterpret_cast<bf16x8*>(&sA[buf][row][col][q][0]) =
            bf16x8{0, 0, 0, 0, 0, 0, 0, 0};
    }
    if (r0 == 0 || r0 == 62) {
        int zr = (r0 == 0) ? 0 : 3;           // gy=-1 or gy=64: zero forever
        for (int i = t; i < 2 * 66 * 4; i += 512) {
            int buf = i / 264, rem = i % 264;
            *reinterpret_cast<bf16x8*>(&sA[buf][zr][rem >> 2][rem & 3][0]) =
                bf16x8{0, 0, 0, 0, 0, 0, 0, 0};
        }
    }

    // weight double-buffer (16 VGPR) + pF double-buffer (32 VGPR)
    bf16x8 w[2][2];
    bf16x8 pf[2][4];
#pragma unroll
    for (int o = 0; o < 2; ++o)               // cc0 tap0 weights -> w[0]
        w[0][o] = *reinterpret_cast<const bf16x8*>(wlane + o * 512);

    auto body = [&](int cc, int cur, int par) {
        const short* wcc = wlane + (size_t)cc * 18432;
        __syncthreads();                      // sA[cur] published (DMA drained)
        if (cc + 1 < 16) stageDMA(cc + 1, cur ^ 1);
        // prime tap0 pF
#pragma unroll
        for (int f = 0; f < 4; ++f)
            pf[0][f] = *reinterpret_cast<const bf16x8*>(
                &sA[cur][row_l][f * 16 + l15][quad][0]);
#pragma unroll
        for (int tap = 0; tap < 9; ++tap) {
            const int pb = tap & 1, pn = pb ^ 1;
            const int cb = (tap + par) & 1, nb = cb ^ 1;
            // prefetch next tap's pF (taps 0-7)
            if (tap < 8) {
                const int dy1 = (tap + 1) / 3, dx1 = (tap + 1) % 3;
#pragma unroll
                for (int f = 0; f < 4; ++f)
                    pf[pn][f] = *reinterpret_cast<const bf16x8*>(
                        &sA[cur][row_l + dy1][f * 16 + l15 + dx1][quad][0]);
            }
            // prefetch next tap's weights (tap8 -> next cc's tap0 by layout)
            const short* nsrc = wcc + (size_t)(tap + 1) * 2048;
#pragma unroll
            for (int o = 0; o < 2; ++o)
                w[nb][o] = *reinterpret_cast<const bf16x8*>(nsrc + o * 512);
            __builtin_amdgcn_sched_barrier(0);   // pin both streams pre-MFMA
#pragma unroll
            for (int o = 0; o < 2; ++o)
#pragma unroll
                for (int f = 0; f < 4; ++f)
                    acc[o][f] = __builtin_amdgcn_mfma_f32_16x16x32_bf16(
                        w[cb][o], pf[pb][f], acc[o][f], 0, 0, 0);
        }
    };

    for (int c2 = 0; c2 < 16; c2 += 2) {
        body(c2,     0, 0);
        body(c2 + 1, 1, 1);
    }

    // epilogue: bias + leaky -> bf16, hid1 chunked [cc4][32768][32].
    const int prow = r0 + row_l;
    const size_t pixbase = (size_t)g * 4096 + (size_t)prow * 64;
#pragma unroll
    for (int o = 0; o < 2; ++o)
#pragma unroll
        for (int reg = 0; reg < 4; ++reg) {
            const int ocg = ocq * 32 + o * 16 + quad * 4 + reg;
            const float bv = bias[g * 128 + ocg];
            const size_t cbase = (size_t)(ocg >> 5) * 32768;
            const int cin = ocg & 31;
#pragma unroll
            for (int f = 0; f < 4; ++f) {
                float v = acc[o][f][reg] + bv;
                v = v >= 0.f ? v : 0.1f * v;
                outp[(cbase + pixbase + f * 16 + l15) * 32 + cin] = f2bs(v);
            }
        }
}

// ---------------------------------------------------------------------------
// conv2_p2: conv1_p2 structure ported to conv2 (128->64). NCC=4, OF=1
// (8 waves = 2 px-rows x 4 oc-16-groups). Input: hid1 chunked
// [cc4][32768][32] (DMA-stageable). Weights: W2p COAL layout
// [g][cc4][tap9][oc64][q4][ic8]. Output: hid2 pixel-major [pix][64]
// (unchanged conv3 input format). Grid 256 x 512 thr.
// ---------------------------------------------------------------------------
__global__ __launch_bounds__(512, 2)
void conv2_p2(const short* __restrict__ inp, const char* __restrict__ wp,
              const float* __restrict__ bias, short* __restrict__ outp)
{
    __shared__ __align__(16) short sA[2][4][66][4][8];   // 33792 B

    const int b  = blockIdx.x;
    const int g  = b & 7;
    const int pt = b >> 3;                    // 0..31
    const int r0 = pt * 2;

    const int t    = threadIdx.x;
    const int wave = t >> 6, lane = t & 63;
    const int l15  = lane & 15, quad = lane >> 4;

    const int row_l = wave & 1;               // px row (0-1)
    const int ocq   = wave >> 1;              // oc 16-group (0-3)

    // W2p layout [g][cc 4][tap 9][oc 64][q 4][ic 8]
    const short* wb    = (const short*)wp + (size_t)g * 4 * 18432;
    const short* wlane = wb + ((size_t)(ocq * 16 + l15) * 4 + quad) * 8;

    auto stageDMA = [&](int cc, int buf) {
        const int row = wave >> 1;
        const int gy  = r0 - 1 + row;
        if (gy >= 0 && gy < 64) {
            const short* src = inp + ((size_t)cc * 32768 + (size_t)g * 4096
                                      + (size_t)gy * 64) * 32
                                   + (size_t)lane * 8;
            const int c4 = (wave & 1) * 2;
            gl_lds16(src + c4 * 512,       &sA[buf][row][1 + c4 * 16][0][0]);
            gl_lds16(src + (c4 + 1) * 512, &sA[buf][row][1 + (c4 + 1) * 16][0][0]);
        }
    };

    f32x4 acc[4];
#pragma unroll
    for (int f = 0; f < 4; ++f)
#pragma unroll
        for (int r = 0; r < 4; ++r) acc[f][r] = 0.f;

    stageDMA(0, 0);
    if (t < 64) {
        int buf = t >> 5, row = (t >> 3) & 3, q = (t >> 1) & 3;
        int col = (t & 1) ? 65 : 0;
        *reinterpret_cast<bf16x8*>(&sA[buf][row][col][q][0]) =
            bf16x8{0, 0, 0, 0, 0, 0, 0, 0};
    }
    if (r0 == 0 || r0 == 62) {
        int zr = (r0 == 0) ? 0 : 3;
        for (int i = t; i < 2 * 66 * 4; i += 512) {
            int buf = i / 264, rem = i % 264;
            *reinterpret_cast<bf16x8*>(&sA[buf][zr][rem >> 2][rem & 3][0]) =
                bf16x8{0, 0, 0, 0, 0, 0, 0, 0};
        }
    }

    bf16x8 w[2];
    bf16x8 pf[2][4];
    w[0] = *reinterpret_cast<const bf16x8*>(wlane);

    auto body = [&](int cc, int cur, int par) {
        const short* wcc = wlane + (size_t)cc * 18432;
        __syncthreads();
        if (cc + 1 < 4) stageDMA(cc + 1, cur ^ 1);
#pragma unroll
        for (int f = 0; f < 4; ++f)
            pf[0][f] = *reinterpret_cast<const bf16x8*>(
                &sA[cur][row_l][f * 16 + l15][quad][0]);
#pragma unroll
        for (int tap = 0; tap < 9; ++tap) {
            const int pb = tap & 1, pn = pb ^ 1;
            const int cb = (tap + par) & 1, nb = cb ^ 1;
            if (tap < 8) {
                const int dy1 = (tap + 1) / 3, dx1 = (tap + 1) % 3;
#pragma unroll
                for (int f = 0; f < 4; ++f)
                    pf[pn][f] = *reinterpret_cast<const bf16x8*>(
                        &sA[cur][row_l + dy1][f * 16 + l15 + dx1][quad][0]);
            }
            // tap8 -> next cc's tap0 by layout; final overread lands in W3p
            // region (valid workspace, value unused).
            w[nb] = *reinterpret_cast<const bf16x8*>(
                wcc + (size_t)(tap + 1) * 2048);
            __builtin_amdgcn_sched_barrier(0);
#pragma unroll
            for (int f = 0; f < 4; ++f)
                acc[f] = __builtin_amdgcn_mfma_f32_16x16x32_bf16(
                    w[cb], pf[pb][f], acc[f], 0, 0, 0);
        }
    };

    for (int c2 = 0; c2 < 4; c2 += 2) {
        body(c2,     0, 0);
        body(c2 + 1, 1, 1);
    }

    // epilogue: bias + leaky -> bf16, hid2 pixel-major [g*4096+pix][64].
    const int prow = r0 + row_l;
    const size_t pixbase = (size_t)g * 4096 + (size_t)prow * 64;
#pragma unroll
    for (int reg = 0; reg < 4; ++reg) {
        const int ocg = ocq * 16 + quad * 4 + reg;
        const float bv = bias[g * 64 + ocg];
#pragma unroll
        for (int f = 0; f < 4; ++f) {
            float v = acc[f][reg] + bv;
            v = v >= 0.f ? v : 0.1f * v;
            outp[(pixbase + f * 16 + l15) * 64 + ocg] = f2bs(v);
        }
    }
}

// ---------------------------------------------------------------------------
// Fused softmax-over-groups + bilinear params + warp + combine (fp32 out).
// gar channels now come from gar_t pixel-major [4096][256]: one gather =
// 512 B contiguous per 32-lane group (4x128B lines, was 16x64B chunked).
// ---------------------------------------------------------------------------
__global__ __launch_bounds__(256)
void warp_combine_kernel(const float* __restrict__ oa,
                         const short* __restrict__ gar_t,
                         const float* __restrict__ mask,
                         float* __restrict__ out)
{
    __shared__ __align__(16) float4 sWts[8][6][8];
    __shared__ __align__(16) int4   sIdx[8][6][8];

    const int t = threadIdx.x;

    if (t < 48) {
        int lp = t / 6;
        int k  = t % 6;
        int p  = blockIdx.x * 8 + lp;
        int x  = p & 63, y = p >> 6;

        float l[8];
        float m = -1e30f;
#pragma unroll
        for (int g = 0; g < 8; ++g) {
            l[g] = oa[(size_t)(g * 18 + 12 + k) * HW + p];
            m = fmaxf(m, l[g]);
        }
        float s = 0.f;
#pragma unroll
        for (int g = 0; g < 8; ++g) { l[g] = __expf(l[g] - m); s += l[g]; }
        float inv = 1.f / s;

#pragma unroll
        for (int g = 0; g < 8; ++g) {
            float a  = l[g] * inv;
            float ox = oa[(size_t)(g * 18 + 2 * k)     * HW + p];
            float oy = oa[(size_t)(g * 18 + 2 * k + 1) * HW + p];
            float sx = fminf(fmaxf(((float)x + ox) * (64.f / 63.f) - 0.5f, 0.f), 63.f);
            float sy = fminf(fmaxf(((float)y + oy) * (64.f / 63.f) - 0.5f, 0.f), 63.f);
            float fx0 = floorf(sx), fy0 = floorf(sy);
            int   x0 = (int)fx0,    y0i = (int)fy0;
            float wx = sx - fx0,    wy = sy - fy0;
            int   x1 = min(x0 + 1, 63), y1 = min(y0i + 1, 63);
            sWts[lp][k][g] = make_float4(a * (1.f - wy) * (1.f - wx),
                                         a * (1.f - wy) * wx,
                                         a * wy * (1.f - wx),
                                         a * wy * wx);
            sIdx[lp][k][g] = make_int4(y0i * 64 + x0, y0i * 64 + x1,
                                       y1  * 64 + x0, y1  * 64 + x1);
        }
    }
    __syncthreads();

    const int lp = t >> 5;
    const int p  = blockIdx.x * 8 + lp;
    const int c0 = (t & 31) * 8;
    const short* ipc = gar_t + c0;            // pixel-major: row stride 256

    float acc[8];
#pragma unroll
    for (int j = 0; j < 8; ++j) acc[j] = 0.f;

    for (int g = 0; g < 8; ++g) {
        float4 m0 = *reinterpret_cast<const float4*>(mask + g * 256 + c0);
        float4 m1 = *reinterpret_cast<const float4*>(mask + g * 256 + c0 + 4);
        float mk[8] = {m0.x, m0.y, m0.z, m0.w, m1.x, m1.y, m1.z, m1.w};
#pragma unroll
        for (int k = 0; k < 6; ++k) {
            float4 w  = sWts[lp][k][g];
            int4   id = sIdx[lp][k][g];
            ushort8v v00 = *reinterpret_cast<const ushort8v*>(ipc + (size_t)id.x * 256);
            ushort8v v01 = *reinterpret_cast<const ushort8v*>(ipc + (size_t)id.y * 256);
            ushort8v v10 = *reinterpret_cast<const ushort8v*>(ipc + (size_t)id.z * 256);
            ushort8v v11 = *reinterpret_cast<const ushort8v*>(ipc + (size_t)id.w * 256);
#pragma unroll
            for (int j = 0; j < 8; ++j) {
                float sv = w.x * bfbits2f(v00[j]) + w.y * bfbits2f(v01[j])
                         + w.z * bfbits2f(v10[j]) + w.w * bfbits2f(v11[j]);
                acc[j] = fmaf(mk[j], sv, acc[j]);
            }
        }
    }
#pragma unroll
    for (int j = 0; j < 8; ++j)
        out[(size_t)(c0 + j) * HW + p] = acc[j];
}

// ---------------------------------------------------------------------------
// Workspace (~28 MB): inp_t 0-4M | W1p 4-9.2M (hid2/hid3 overlay dead W1p)
// | oa 10.5-12.9M | W2p 14M | W3p 15.5M | W4p 16M | hid1 17-25M |
// gar_t 26-28M.
// ---------------------------------------------------------------------------
extern "C" void kernel_launch(void* const* d_in, const int* in_sizes, int n_in,
                              void* d_out, int out_size, void* d_ws, size_t ws_size,
                              hipStream_t stream)
{
    (void)in_sizes; (void)n_in; (void)out_size; (void)ws_size;
    const float* gar  = (const float*)d_in[0];
    const float* cond = (const float*)d_in[1];
    const float* mask = (const float*)d_in[2];
    const float* W1   = (const float*)d_in[3];
    const float* b1   = (const float*)d_in[4];
    const float* W2   = (const float*)d_in[5];
    const float* b2   = (const float*)d_in[6];
    const float* W3   = (const float*)d_in[7];
    const float* b3   = (const float*)d_in[8];
    const float* W4   = (const float*)d_in[9];
    const float* b4   = (const float*)d_in[10];
    float* out = (float*)d_out;

    char* ws = (char*)d_ws;
    short* inp_t  = (short*)(ws);
    char*  W1p    = ws + (4u << 20);
    short* hid2_t = (short*)(ws + (4u << 20));          // overlays dead W1p
    short* hid3_t = (short*)(ws + (8u << 20));          // overlays dead W1p
    float* oa     = (float*)(ws + (10u << 20) + (512u << 10));
    char*  W2p    = ws + (14u << 20);
    char*  W3p    = ws + (15u << 20) + (512u << 10);
    char*  W4p    = ws + (16u << 20);
    short* hid1_t = (short*)(ws + (17u << 20));
    short* gar_t  = (short*)(ws + (26u << 20));

    // 312 weight-pack blocks + 2048 input-transpose blocks, one launch
    pack_all<<<2360, 256, 0, stream>>>(gar, cond, W1, W2, W3, W4,
                                       inp_t, gar_t, W1p, W2p, W3p, W4p);

    // conv1: dual-stream pipelined, full-K, chunked bf16 out (round-6 struct)
    conv1_p2<<<256, 512, 0, stream>>>(inp_t, W1p, b1, hid1_t);
    // conv2: conv1_p2-style port (chunked input DMA + reg pipeline)
    conv2_p2<<<256, 512, 0, stream>>>(hid1_t, W2p, b2, hid2_t);
    // conv3: 64->32, ROWS=2, BN=32, OF=1, NT=1, NW=4, PIPE=1 (unchanged)
    conv_mfma<64, 32, 32, 2, 1, 1, 4, 1, true, true, false>
        <<<256, 256, 0, stream>>>(hid2_t, W3p, b3, hid3_t);
    // conv4: 32->18 (pad 32), ROWS=2, BN=32, OF=1, NT=1, NW=4 (unchanged)
    conv_mfma<32, 18, 32, 2, 1, 1, 4, 1, false, false, true>
        <<<256, 256, 0, stream>>>(hid3_t, W4p, b4, oa);

    warp_combine_kernel<<<512, 256, 0, stream>>>(oa, gar_t, mask, out);
}

// Round 8
// 194.711 us; speedup vs baseline: 1.0293x; 1.0293x over previous
//
#include <hip/hip_runtime.h>
#include <hip/hip_bf16.h>

typedef __hip_bfloat16 bf16;
typedef unsigned short ushort8v __attribute__((ext_vector_type(8)));
typedef short  s16x4  __attribute__((ext_vector_type(4)));
typedef short  bf16x8 __attribute__((ext_vector_type(8)));   // 8 bf16 (4 VGPRs)
typedef float  f32x4  __attribute__((ext_vector_type(4)));

#define HW 4096
#define IMG_W 64

__device__ __forceinline__ float bfbits2f(unsigned short u) {
    return __uint_as_float(((unsigned int)u) << 16);
}
__device__ __forceinline__ short f2bs(float f) {
    bf16 h = __float2bfloat16(f);
    return *reinterpret_cast<short*>(&h);
}

// async global->LDS, 16B per lane. LDS dest = wave-uniform base + lane*16;
// the GLOBAL source address is per-lane (m173 pattern).
__device__ __forceinline__ void gl_lds16(const void* g, void* s) {
    __builtin_amdgcn_global_load_lds(
        (const __attribute__((address_space(1))) unsigned int*)g,
        (__attribute__((address_space(3))) unsigned int*)s, 16, 0, 0);
}

// ---------------------------------------------------------------------------
// pack_input: concat(gar,cond) fp32 [512][4096] -> inp_t bf16 chunked
// [cc=16][pix=4096][32ch] (conv1 DMA layout) AND gar_t bf16 pixel-major
// [4096 px][256 ch] (warp_combine gather layout: a 32-lane channel-group
// reads 512 B contiguous -> 4x128B cache lines per gather).
// ---------------------------------------------------------------------------
__device__ void pack_input_dev(const float* __restrict__ gar,
                               const float* __restrict__ cond,
                               short* __restrict__ outp,
                               short* __restrict__ gart, int bx2, float* tile)
{
    int bx = bx2 & 127;                // px tile (128)
    int by = bx2 >> 7;                 // ch tile (16) == cc chunk
    int tx = threadIdx.x & 31;
    int ty = threadIdx.x >> 5;
#pragma unroll
    for (int i = 0; i < 4; ++i) {
        int c = by * 32 + ty + i * 8;
        const float* src = (c < 256) ? (gar + (size_t)c * HW)
                                     : (cond + (size_t)(c - 256) * HW);
        tile[(ty + i * 8) * 33 + tx] = src[bx * 32 + tx];
    }
    __syncthreads();
#pragma unroll
    for (int i = 0; i < 4; ++i) {
        int p = bx * 32 + ty + i * 8;
        short v = f2bs(tile[tx * 33 + ty + i * 8]);
        outp[((size_t)by * 4096 + p) * 32 + tx] = v;
        if (by < 8)                    // gar channels only (block-uniform)
            gart[(size_t)p * 256 + by * 32 + tx] = v;
    }
}

// ---------------------------------------------------------------------------
// pack_w: W fp32 [G][CREAL][CIN][3][3] -> bf16 blocks.
// COAL=false (conv3-4): [g][nt][cc][tap 9][q 4][oc BN][8 ic]   (old layout)
// COAL=true  (conv1-2): [g][nt][cc][tap 9][oc BN][q 4][8 ic]   -> a wave's
//   64-lane weight-fragment load is one contiguous span.
// BLKB = 9*4*BN*16 bytes either way.
// ---------------------------------------------------------------------------
template<int CIN, int CREAL, int BN, int NT, bool COAL>
__device__ void pack_w_dev(const float* __restrict__ wgt, char* __restrict__ wp,
                           int bx, short* sT)
{
    constexpr int NCC  = CIN / 32;
    constexpr int BLKB = 9 * 4 * BN * 16;

    const int t  = threadIdx.x;
    const int cc = bx % NCC;
    const int nt = (bx / NCC) % NT;
    const int g  = bx / (NT * NCC);

    for (int i = t; i < BLKB / 8; i += 256)
        reinterpret_cast<s16x4*>(sT)[i] = s16x4{0, 0, 0, 0};
    __syncthreads();

    int ocmax = CREAL - nt * BN; if (ocmax > BN) ocmax = BN;
    const size_t base = ((size_t)(g * CREAL + nt * BN) * CIN + cc * 32) * 9;
    for (int i = t; i < ocmax * 288; i += 256) {
        int oc = i / 288;
        int r  = i % 288;                      // ic*9 + tap
        int ic = r / 9, tap = r % 9;
        size_t idx;
        if (COAL) idx = (size_t)(((tap * BN + oc) * 4 + (ic >> 3)) * 8 + (ic & 7));
        else      idx = (size_t)(((tap * 4 + (ic >> 3)) * BN + oc) * 8 + (ic & 7));
        sT[idx] = f2bs(wgt[base + (size_t)oc * CIN * 9 + r]);
    }
    __syncthreads();

    const s16x4* src = reinterpret_cast<const s16x4*>(sT);
    s16x4* dst = reinterpret_cast<s16x4*>(wp + (size_t)bx * BLKB);
    for (int i = t; i < BLKB / 8; i += 256)
        dst[i] = src[i];
}

// All packing in one launch (block-range dispatch; branch is block-uniform).
__global__ __launch_bounds__(256)
void pack_all(const float* __restrict__ gar, const float* __restrict__ cond,
              const float* __restrict__ W1, const float* __restrict__ W2,
              const float* __restrict__ W3, const float* __restrict__ W4,
              short* inp_t, short* gar_t,
              char* W1p, char* W2p, char* W3p, char* W4p)
{
    __shared__ __align__(16) short sbuf[9 * 4 * 64 * 8];   // 36864 B
    int bx = blockIdx.x;
    if (bx < 256)      pack_w_dev<512, 128, 64, 2, true >(W1, W1p, bx,       sbuf);
    else if (bx < 288) pack_w_dev<128,  64, 64, 1, true >(W2, W2p, bx - 256, sbuf);
    else if (bx < 304) pack_w_dev< 64,  32, 32, 1, false>(W3, W3p, bx - 288, sbuf);
    else if (bx < 312) pack_w_dev< 32,  18, 32, 1, false>(W4, W4p, bx - 304, sbuf);
    else pack_input_dev(gar, cond, inp_t, gar_t, bx - 312, (float*)sbuf);
}

// ---------------------------------------------------------------------------
// Implicit-GEMM 3x3 SAME conv, bf16 MFMA 16x16x32, conflict-free LDS.
// (old template — still used for conv3/conv4; input layout [pix][ICP])
// ---------------------------------------------------------------------------
template<int ICP, int CREAL, int BN, int ROWS, int OF, int NT, int NW, int PIPE,
         bool PIXMAJ_OUT, bool LEAKY, bool OUT_F32>
__global__ __launch_bounds__(NW * 64, 2)
void conv_mfma(const short* __restrict__ inp, const char* __restrict__ wp,
               const float* __restrict__ bias, void* __restrict__ outv)
{
    constexpr int NCC  = ICP / 32;
    constexpr int HALO = ROWS + 2;
    constexpr int NPT  = 4096 / (ROWS * 64);
    constexpr int BLKB = 9 * 4 * BN * 16;
    constexpr int RNDS = BLKB / 1024;
    constexpr int NBUF = (PIPE && NCC > 1) ? 2 : 1;
    constexpr int SMAX = (HALO + NW - 1) / NW;

    __shared__ __align__(16) short sA[HALO][4][68][8];
    __shared__ __align__(16) char  sBraw[NBUF][BLKB];

    const int b  = blockIdx.x;
    const int g  = b & 7;                     // XCD swizzle: group per XCD
    const int r_ = b >> 3;
    const int pt = r_ % NPT;
    const int nt = r_ / NPT;
    const int r0 = pt * ROWS;

    const int t    = threadIdx.x;
    const int wave = t >> 6, lane = t & 63;
    const int l15  = lane & 15, quad = lane >> 4;

    int row_l, ocw;
    if (NW == 8) {
        if (ROWS == 4) { row_l = wave >> 1; ocw = (wave & 1) * (BN / 2); }
        else           { row_l = wave >> 2; ocw = (wave & 3) * (BN / 4); }
    } else {
        row_l = (ROWS == 4) ? wave : (wave & 1);
        ocw   = (ROWS == 4) ? 0 : (wave >> 1) * (BN / 2);
    }

    const size_t gpix = (ICP == 512) ? 0 : ((size_t)g * 4096);
    const char*  wb   = wp + (size_t)((g * NT + nt) * NCC) * BLKB;

    // sA staging: thread -> (col, row-slice); rows j = r2, r2+NW, ...
    const int acol = t & 63;
    const int r2   = t >> 6;

    bf16x8 pre[SMAX][4];

    auto stageA_load = [&](int cc) {
#pragma unroll
        for (int s = 0; s < SMAX; ++s) {
            int j = r2 + s * NW;
            if (j < HALO) {
                int gy = r0 - 1 + j;
                if (gy >= 0 && gy < 64) {
                    const short* sp = inp + ((gpix + gy * 64 + acol) * ICP + cc * 32);
#pragma unroll
                    for (int q = 0; q < 4; ++q)
                        pre[s][q] = *reinterpret_cast<const bf16x8*>(sp + q * 8);
                } else {
#pragma unroll
                    for (int q = 0; q < 4; ++q)
                        pre[s][q] = bf16x8{0, 0, 0, 0, 0, 0, 0, 0};
                }
            }
        }
    };
    auto stageA_write = [&]() {
#pragma unroll
        for (int s = 0; s < SMAX; ++s) {
            int j = r2 + s * NW;
            if (j < HALO) {
#pragma unroll
                for (int q = 0; q < 4; ++q)
                    *reinterpret_cast<bf16x8*>(&sA[j][q][acol + 1][0]) = pre[s][q];
            }
        }
    };
    auto stageB = [&](int cc) {
        const char* wsrc = wb + (size_t)cc * BLKB;
        char* sbb = (char*)sBraw[(NBUF == 2) ? (cc & 1) : 0];
        for (int r = wave; r < RNDS; r += NW)
            gl_lds16(wsrc + r * 1024 + lane * 16, sbb + r * 1024);
    };

    f32x4 acc[OF][4];
#pragma unroll
    for (int o = 0; o < OF; ++o)
#pragma unroll
        for (int p = 0; p < 4; ++p)
#pragma unroll
            for (int r = 0; r < 4; ++r) acc[o][p][r] = 0.f;

    // zero the x-pad column units (col index 0 and 65) once
    if (t < HALO * 8) {
        int row = t >> 3, q = (t >> 1) & 3, cp = (t & 1) ? 65 : 0;
        *reinterpret_cast<bf16x8*>(&sA[row][q][cp][0]) =
            bf16x8{0, 0, 0, 0, 0, 0, 0, 0};
    }

    // prologue: stage phase 0
    stageB(0);
    stageA_load(0);
    stageA_write();

    for (int cc = 0; cc < NCC; ++cc) {
        __syncthreads();               // sB(cc) drained, sA(cc) visible
        if (cc + 1 < NCC) {
            if (PIPE) stageB(cc + 1);  // dbuf: DMA into alternate buffer now
            stageA_load(cc + 1);       // global -> regs, no LDS touch
        }
        const bf16x8* sBv = reinterpret_cast<const bf16x8*>(
            sBraw[(NBUF == 2) ? (cc & 1) : 0]);

#pragma unroll
        for (int dy = 0; dy < 3; ++dy) {
#pragma unroll
            for (int dx = 0; dx < 3; ++dx) {
                bf16x8 pF[4];
#pragma unroll
                for (int p = 0; p < 4; ++p)
                    pF[p] = *reinterpret_cast<const bf16x8*>(
                        &sA[row_l + dy][quad][p * 16 + l15 + dx][0]);
                bf16x8 wF[OF];
#pragma unroll
                for (int o = 0; o < OF; ++o)
                    wF[o] = sBv[((dy * 3 + dx) * 4 + quad) * BN + ocw + o * 16 + l15];
#pragma unroll
                for (int o = 0; o < OF; ++o)
#pragma unroll
                    for (int p = 0; p < 4; ++p)
                        acc[o][p] = __builtin_amdgcn_mfma_f32_16x16x32_bf16(
                            wF[o], pF[p], acc[o][p], 0, 0, 0);
            }
        }
        __syncthreads();               // all reads of sA(cc)/sB(cc) done
        if (cc + 1 < NCC) {
            if (!PIPE) stageB(cc + 1); // single-buf: DMA into the freed buffer
            stageA_write();
        }
    }

    // ---- epilogue. C/D: m(oc) = quad*4+reg, n(pixel) = l15.
    const int prow = r0 + row_l;
#pragma unroll
    for (int o = 0; o < OF; ++o)
#pragma unroll
        for (int reg = 0; reg < 4; ++reg) {
            const int ocl = ocw + o * 16 + quad * 4 + reg;
            const int ocg = nt * BN + ocl;
            if (ocg < CREAL) {
                const float bv = bias[g * CREAL + ocg];
                if (PIXMAJ_OUT) {
                    short* outp = (short*)outv;
                    const size_t pixbase = ((size_t)g * 4096 + prow * 64);
#pragma unroll
                    for (int p = 0; p < 4; ++p) {
                        float v = acc[o][p][reg] + bv;
                        if (LEAKY) v = v >= 0.f ? v : 0.1f * v;
                        outp[(pixbase + p * 16 + l15) * (NT * BN) + ocg] = f2bs(v);
                    }
                } else if (OUT_F32) {
                    float* outp = (float*)outv;
                    const size_t base = ((size_t)(g * CREAL + ocg)) * HW + prow * IMG_W;
#pragma unroll
                    for (int p = 0; p < 4; ++p) {
                        float v = acc[o][p][reg] + bv;
                        if (LEAKY) v = v >= 0.f ? v : 0.1f * v;
                        outp[base + p * 16 + l15] = v;
                    }
                } else {
                    short* outp = (short*)outv;
                    const size_t base = ((size_t)(g * CREAL + ocg)) * HW + prow * IMG_W;
#pragma unroll
                    for (int p = 0; p < 4; ++p) {
                        float v = acc[o][p][reg] + bv;
                        if (LEAKY) v = v >= 0.f ? v : 0.1f * v;
                        outp[base + p * 16 + l15] = f2bs(v);
                    }
                }
            }
        }
}

// ---------------------------------------------------------------------------
// conv1_p2: dual-stream register pipeline, full-K. EXACT round-6 structure
// (verified 49.6us) incl. the pixel-major [pix][128] epilogue — round 7's
// chunked-output epilogue cost +6.2us and is reverted.
// ---------------------------------------------------------------------------
__global__ __launch_bounds__(512, 2)
void conv1_p2(const short* __restrict__ inp, const char* __restrict__ wp,
              const float* __restrict__ bias, short* __restrict__ outp)
{
    __shared__ __align__(16) short sA[2][4][66][4][8];   // 33792 B

    const int b  = blockIdx.x;
    const int g  = b & 7;                     // XCD swizzle: group per XCD
    const int pt = b >> 3;                    // 0..31
    const int r0 = pt * 2;

    const int t    = threadIdx.x;
    const int wave = t >> 6, lane = t & 63;
    const int l15  = lane & 15, quad = lane >> 4;

    const int row_l = wave & 1;               // px row (0-1)
    const int ocq   = wave >> 1;              // oc quarter (0-3)
    const int ntw   = ocq >> 1;               // W1p nt half
    const int ocw64 = (ocq & 1) * 32;         // oc base within nt

    // W1p layout [g][nt][cc 16][tap 9][oc 64][q 4][ic 8]
    const short* wb    = (const short*)wp + (size_t)(g * 2 + ntw) * 16 * 18432;
    const short* wlane = wb + ((size_t)(ocw64 + l15) * 4 + quad) * 8;

    // staging: wave w -> halo row (w>>1), column half (w&1): 2 x 1KB DMA
    auto stageDMA = [&](int cc, int buf) {
        const int row = wave >> 1;
        const int gy  = r0 - 1 + row;
        if (gy >= 0 && gy < 64) {
            const short* src = inp + ((size_t)cc * 4096 + (size_t)gy * 64) * 32
                                   + (size_t)lane * 8;
            const int c4 = (wave & 1) * 2;
            gl_lds16(src + c4 * 512,       &sA[buf][row][1 + c4 * 16][0][0]);
            gl_lds16(src + (c4 + 1) * 512, &sA[buf][row][1 + (c4 + 1) * 16][0][0]);
        }
    };

    f32x4 acc[2][4];
#pragma unroll
    for (int o = 0; o < 2; ++o)
#pragma unroll
        for (int f = 0; f < 4; ++f)
#pragma unroll
            for (int r = 0; r < 4; ++r) acc[o][f][r] = 0.f;

    // prologue: DMA(0) into buf0, zero x-pads (both bufs) + OOB rows
    stageDMA(0, 0);
    if (t < 64) {
        int buf = t >> 5, row = (t >> 3) & 3, q = (t >> 1) & 3;
        int col = (t & 1) ? 65 : 0;
        *reinterpret_cast<bf16x8*>(&sA[buf][row][col][q][0]) =
            bf16x8{0, 0, 0, 0, 0, 0, 0, 0};
    }
    if (r0 == 0 || r0 == 62) {
        int zr = (r0 == 0) ? 0 : 3;           // gy=-1 or gy=64: zero forever
        for (int i = t; i < 2 * 66 * 4; i += 512) {
            int buf = i / 264, rem = i % 264;
            *reinterpret_cast<bf16x8*>(&sA[buf][zr][rem >> 2][rem & 3][0]) =
                bf16x8{0, 0, 0, 0, 0, 0, 0, 0};
        }
    }

    // weight double-buffer (16 VGPR) + pF double-buffer (32 VGPR)
    bf16x8 w[2][2];
    bf16x8 pf[2][4];
#pragma unroll
    for (int o = 0; o < 2; ++o)               // cc0 tap0 weights -> w[0]
        w[0][o] = *reinterpret_cast<const bf16x8*>(wlane + o * 512);

    auto body = [&](int cc, int cur, int par) {
        const short* wcc = wlane + (size_t)cc * 18432;
        __syncthreads();                      // sA[cur] published (DMA drained)
        if (cc + 1 < 16) stageDMA(cc + 1, cur ^ 1);
        // prime tap0 pF
#pragma unroll
        for (int f = 0; f < 4; ++f)
            pf[0][f] = *reinterpret_cast<const bf16x8*>(
                &sA[cur][row_l][f * 16 + l15][quad][0]);
#pragma unroll
        for (int tap = 0; tap < 9; ++tap) {
            const int pb = tap & 1, pn = pb ^ 1;
            const int cb = (tap + par) & 1, nb = cb ^ 1;
            // prefetch next tap's pF (taps 0-7)
            if (tap < 8) {
                const int dy1 = (tap + 1) / 3, dx1 = (tap + 1) % 3;
#pragma unroll
                for (int f = 0; f < 4; ++f)
                    pf[pn][f] = *reinterpret_cast<const bf16x8*>(
                        &sA[cur][row_l + dy1][f * 16 + l15 + dx1][quad][0]);
            }
            // prefetch next tap's weights (tap8 -> next cc's tap0 by layout)
            const short* nsrc = wcc + (size_t)(tap + 1) * 2048;
#pragma unroll
            for (int o = 0; o < 2; ++o)
                w[nb][o] = *reinterpret_cast<const bf16x8*>(nsrc + o * 512);
            __builtin_amdgcn_sched_barrier(0);   // pin both streams pre-MFMA
#pragma unroll
            for (int o = 0; o < 2; ++o)
#pragma unroll
                for (int f = 0; f < 4; ++f)
                    acc[o][f] = __builtin_amdgcn_mfma_f32_16x16x32_bf16(
                        w[cb][o], pf[pb][f], acc[o][f], 0, 0, 0);
        }
    };

    for (int c2 = 0; c2 < 16; c2 += 2) {
        body(c2,     0, 0);
        body(c2 + 1, 1, 1);
    }

    // epilogue (round-6 verified): bias + leaky -> bf16, out [pix][128].
    const int prow = r0 + row_l;
    const size_t pixbase = (size_t)g * 4096 + (size_t)prow * 64;
#pragma unroll
    for (int o = 0; o < 2; ++o)
#pragma unroll
        for (int reg = 0; reg < 4; ++reg) {
            const int ocg = ocq * 32 + o * 16 + quad * 4 + reg;
            const float bv = bias[g * 128 + ocg];
#pragma unroll
            for (int f = 0; f < 4; ++f) {
                float v = acc[o][f][reg] + bv;
                v = v >= 0.f ? v : 0.1f * v;
                outp[(pixbase + f * 16 + l15) * 128 + ocg] = f2bs(v);
            }
        }
}

// ---------------------------------------------------------------------------
// conv2_p2: conv1_p2 structure for conv2 (128->64). NCC=4, OF=1 (8 waves =
// 2 px-rows x 4 oc-16-groups). Input: hid1 PIXEL-MAJOR [g*4096+pix][128] —
// staged via per-lane gl_lds16 source addresses (m173: global src is
// per-lane; LDS dest stays linear): lane l -> pixel c4*16+(l>>2), chunk
// channels (l&3)*8. Weights: W2p COAL [g][cc4][tap9][oc64][q4][ic8].
// Output: hid2 pixel-major [pix][64]. Grid 256 x 512 thr.
// ---------------------------------------------------------------------------
__global__ __launch_bounds__(512, 2)
void conv2_p2(const short* __restrict__ inp, const char* __restrict__ wp,
              const float* __restrict__ bias, short* __restrict__ outp)
{
    __shared__ __align__(16) short sA[2][4][66][4][8];   // 33792 B

    const int b  = blockIdx.x;
    const int g  = b & 7;
    const int pt = b >> 3;                    // 0..31
    const int r0 = pt * 2;

    const int t    = threadIdx.x;
    const int wave = t >> 6, lane = t & 63;
    const int l15  = lane & 15, quad = lane >> 4;

    const int row_l = wave & 1;               // px row (0-1)
    const int ocq   = wave >> 1;              // oc 16-group (0-3)

    // W2p layout [g][cc 4][tap 9][oc 64][q 4][ic 8]
    const short* wb    = (const short*)wp + (size_t)g * 4 * 18432;
    const short* wlane = wb + ((size_t)(ocq * 16 + l15) * 4 + quad) * 8;

    // per-lane source: pixel-major row gy, pixel c4*16+(lane>>2), 16B of
    // channels cc*32 + (lane&3)*8.
    auto stageDMA = [&](int cc, int buf) {
        const int row = wave >> 1;
        const int gy  = r0 - 1 + row;
        if (gy >= 0 && gy < 64) {
            const short* rowb = inp + ((size_t)g * 4096 + (size_t)gy * 64) * 128
                                    + cc * 32 + (lane & 3) * 8;
            const int c4 = (wave & 1) * 2;
            gl_lds16(rowb + (size_t)(c4 * 16 + (lane >> 2)) * 128,
                     &sA[buf][row][1 + c4 * 16][0][0]);
            gl_lds16(rowb + (size_t)((c4 + 1) * 16 + (lane >> 2)) * 128,
                     &sA[buf][row][1 + (c4 + 1) * 16][0][0]);
        }
    };

    f32x4 acc[4];
#pragma unroll
    for (int f = 0; f < 4; ++f)
#pragma unroll
        for (int r = 0; r < 4; ++r) acc[f][r] = 0.f;

    stageDMA(0, 0);
    if (t < 64) {
        int buf = t >> 5, row = (t >> 3) & 3, q = (t >> 1) & 3;
        int col = (t & 1) ? 65 : 0;
        *reinterpret_cast<bf16x8*>(&sA[buf][row][col][q][0]) =
            bf16x8{0, 0, 0, 0, 0, 0, 0, 0};
    }
    if (r0 == 0 || r0 == 62) {
        int zr = (r0 == 0) ? 0 : 3;
        for (int i = t; i < 2 * 66 * 4; i += 512) {
            int buf = i / 264, rem = i % 264;
            *reinterpret_cast<bf16x8*>(&sA[buf][zr][rem >> 2][rem & 3][0]) =
                bf16x8{0, 0, 0, 0, 0, 0, 0, 0};
        }
    }

    bf16x8 w[2];
    bf16x8 pf[2][4];
    w[0] = *reinterpret_cast<const bf16x8*>(wlane);

    auto body = [&](int cc, int cur, int par) {
        const short* wcc = wlane + (size_t)cc * 18432;
        __syncthreads();
        if (cc + 1 < 4) stageDMA(cc + 1, cur ^ 1);
#pragma unroll
        for (int f = 0; f < 4; ++f)
            pf[0][f] = *reinterpret_cast<const bf16x8*>(
                &sA[cur][row_l][f * 16 + l15][quad][0]);
#pragma unroll
        for (int tap = 0; tap < 9; ++tap) {
            const int pb = tap & 1, pn = pb ^ 1;
            const int cb = (tap + par) & 1, nb = cb ^ 1;
            if (tap < 8) {
                const int dy1 = (tap + 1) / 3, dx1 = (tap + 1) % 3;
#pragma unroll
                for (int f = 0; f < 4; ++f)
                    pf[pn][f] = *reinterpret_cast<const bf16x8*>(
                        &sA[cur][row_l + dy1][f * 16 + l15 + dx1][quad][0]);
            }
            // tap8 -> next cc's tap0 by layout; final overread lands in
            // dead workspace past W2p (value unused).
            w[nb] = *reinterpret_cast<const bf16x8*>(
                wcc + (size_t)(tap + 1) * 2048);
            __builtin_amdgcn_sched_barrier(0);
#pragma unroll
            for (int f = 0; f < 4; ++f)
                acc[f] = __builtin_amdgcn_mfma_f32_16x16x32_bf16(
                    w[cb], pf[pb][f], acc[f], 0, 0, 0);
        }
    };

    for (int c2 = 0; c2 < 4; c2 += 2) {
        body(c2,     0, 0);
        body(c2 + 1, 1, 1);
    }

    // epilogue: bias + leaky -> bf16, hid2 pixel-major [g*4096+pix][64].
    const int prow = r0 + row_l;
    const size_t pixbase = (size_t)g * 4096 + (size_t)prow * 64;
#pragma unroll
    for (int reg = 0; reg < 4; ++reg) {
        const int ocg = ocq * 16 + quad * 4 + reg;
        const float bv = bias[g * 64 + ocg];
#pragma unroll
        for (int f = 0; f < 4; ++f) {
            float v = acc[f][reg] + bv;
            v = v >= 0.f ? v : 0.1f * v;
            outp[(pixbase + f * 16 + l15) * 64 + ocg] = f2bs(v);
        }
    }
}

// ---------------------------------------------------------------------------
// Fused softmax-over-groups + bilinear params + warp + combine (fp32 out).
// gar channels from gar_t pixel-major [4096][256]: one gather = 512 B
// contiguous per 32-lane group (4x128B lines).
// ---------------------------------------------------------------------------
__global__ __launch_bounds__(256)
void warp_combine_kernel(const float* __restrict__ oa,
                         const short* __restrict__ gar_t,
                         const float* __restrict__ mask,
                         float* __restrict__ out)
{
    __shared__ __align__(16) float4 sWts[8][6][8];
    __shared__ __align__(16) int4   sIdx[8][6][8];

    const int t = threadIdx.x;

    if (t < 48) {
        int lp = t / 6;
        int k  = t % 6;
        int p  = blockIdx.x * 8 + lp;
        int x  = p & 63, y = p >> 6;

        float l[8];
        float m = -1e30f;
#pragma unroll
        for (int g = 0; g < 8; ++g) {
            l[g] = oa[(size_t)(g * 18 + 12 + k) * HW + p];
            m = fmaxf(m, l[g]);
        }
        float s = 0.f;
#pragma unroll
        for (int g = 0; g < 8; ++g) { l[g] = __expf(l[g] - m); s += l[g]; }
        float inv = 1.f / s;

#pragma unroll
        for (int g = 0; g < 8; ++g) {
            float a  = l[g] * inv;
            float ox = oa[(size_t)(g * 18 + 2 * k)     * HW + p];
            float oy = oa[(size_t)(g * 18 + 2 * k + 1) * HW + p];
            float sx = fminf(fmaxf(((float)x + ox) * (64.f / 63.f) - 0.5f, 0.f), 63.f);
            float sy = fminf(fmaxf(((float)y + oy) * (64.f / 63.f) - 0.5f, 0.f), 63.f);
            float fx0 = floorf(sx), fy0 = floorf(sy);
            int   x0 = (int)fx0,    y0i = (int)fy0;
            float wx = sx - fx0,    wy = sy - fy0;
            int   x1 = min(x0 + 1, 63), y1 = min(y0i + 1, 63);
            sWts[lp][k][g] = make_float4(a * (1.f - wy) * (1.f - wx),
                                         a * (1.f - wy) * wx,
                                         a * wy * (1.f - wx),
                                         a * wy * wx);
            sIdx[lp][k][g] = make_int4(y0i * 64 + x0, y0i * 64 + x1,
                                       y1  * 64 + x0, y1  * 64 + x1);
        }
    }
    __syncthreads();

    const int lp = t >> 5;
    const int p  = blockIdx.x * 8 + lp;
    const int c0 = (t & 31) * 8;
    const short* ipc = gar_t + c0;            // pixel-major: row stride 256

    float acc[8];
#pragma unroll
    for (int j = 0; j < 8; ++j) acc[j] = 0.f;

    for (int g = 0; g < 8; ++g) {
        float4 m0 = *reinterpret_cast<const float4*>(mask + g * 256 + c0);
        float4 m1 = *reinterpret_cast<const float4*>(mask + g * 256 + c0 + 4);
        float mk[8] = {m0.x, m0.y, m0.z, m0.w, m1.x, m1.y, m1.z, m1.w};
#pragma unroll
        for (int k = 0; k < 6; ++k) {
            float4 w  = sWts[lp][k][g];
            int4   id = sIdx[lp][k][g];
            ushort8v v00 = *reinterpret_cast<const ushort8v*>(ipc + (size_t)id.x * 256);
            ushort8v v01 = *reinterpret_cast<const ushort8v*>(ipc + (size_t)id.y * 256);
            ushort8v v10 = *reinterpret_cast<const ushort8v*>(ipc + (size_t)id.z * 256);
            ushort8v v11 = *reinterpret_cast<const ushort8v*>(ipc + (size_t)id.w * 256);
#pragma unroll
            for (int j = 0; j < 8; ++j) {
                float sv = w.x * bfbits2f(v00[j]) + w.y * bfbits2f(v01[j])
                         + w.z * bfbits2f(v10[j]) + w.w * bfbits2f(v11[j]);
                acc[j] = fmaf(mk[j], sv, acc[j]);
            }
        }
    }
#pragma unroll
    for (int j = 0; j < 8; ++j)
        out[(size_t)(c0 + j) * HW + p] = acc[j];
}

// ---------------------------------------------------------------------------
// Workspace (~28 MB): inp_t 0-4M | W1p 4-9.2M (hid2/hid3 overlay dead W1p)
// | oa 10.5-12.9M | W2p 14M | W3p 15.5M | W4p 16M | hid1 17-25M |
// gar_t 26-28M.
// ---------------------------------------------------------------------------
extern "C" void kernel_launch(void* const* d_in, const int* in_sizes, int n_in,
                              void* d_out, int out_size, void* d_ws, size_t ws_size,
                              hipStream_t stream)
{
    (void)in_sizes; (void)n_in; (void)out_size; (void)ws_size;
    const float* gar  = (const float*)d_in[0];
    const float* cond = (const float*)d_in[1];
    const float* mask = (const float*)d_in[2];
    const float* W1   = (const float*)d_in[3];
    const float* b1   = (const float*)d_in[4];
    const float* W2   = (const float*)d_in[5];
    const float* b2   = (const float*)d_in[6];
    const float* W3   = (const float*)d_in[7];
    const float* b3   = (const float*)d_in[8];
    const float* W4   = (const float*)d_in[9];
    const float* b4   = (const float*)d_in[10];
    float* out = (float*)d_out;

    char* ws = (char*)d_ws;
    short* inp_t  = (short*)(ws);
    char*  W1p    = ws + (4u << 20);
    short* hid2_t = (short*)(ws + (4u << 20));          // overlays dead W1p
    short* hid3_t = (short*)(ws + (8u << 20));          // overlays dead W1p
    float* oa     = (float*)(ws + (10u << 20) + (512u << 10));
    char*  W2p    = ws + (14u << 20);
    char*  W3p    = ws + (15u << 20) + (512u << 10);
    char*  W4p    = ws + (16u << 20);
    short* hid1_t = (short*)(ws + (17u << 20));
    short* gar_t  = (short*)(ws + (26u << 20));

    // 312 weight-pack blocks + 2048 input-transpose blocks, one launch
    pack_all<<<2360, 256, 0, stream>>>(gar, cond, W1, W2, W3, W4,
                                       inp_t, gar_t, W1p, W2p, W3p, W4p);

    // conv1: round-6 verified kernel (pixel-major out)
    conv1_p2<<<256, 512, 0, stream>>>(inp_t, W1p, b1, hid1_t);
    // conv2: conv1_p2-style, per-lane DMA staging from pixel-major hid1
    conv2_p2<<<256, 512, 0, stream>>>(hid1_t, W2p, b2, hid2_t);
    // conv3: 64->32, ROWS=2, BN=32, OF=1, NT=1, NW=4, PIPE=1 (unchanged)
    conv_mfma<64, 32, 32, 2, 1, 1, 4, 1, true, true, false>
        <<<256, 256, 0, stream>>>(hid2_t, W3p, b3, hid3_t);
    // conv4: 32->18 (pad 32), ROWS=2, BN=32, OF=1, NT=1, NW=4 (unchanged)
    conv_mfma<32, 18, 32, 2, 1, 1, 4, 1, false, false, true>
        <<<256, 256, 0, stream>>>(hid3_t, W4p, b4, oa);

    warp_combine_kernel<<<512, 256, 0, stream>>>(oa, gar_t, mask, out);
}

// Round 9
// 188.744 us; speedup vs baseline: 1.0618x; 1.0316x over previous
//
#include <hip/hip_runtime.h>
#include <hip/hip_bf16.h>

typedef __hip_bfloat16 bf16;
typedef unsigned short ushort8v __attribute__((ext_vector_type(8)));
typedef short  s16x4  __attribute__((ext_vector_type(4)));
typedef short  bf16x8 __attribute__((ext_vector_type(8)));   // 8 bf16 (4 VGPRs)
typedef float  f32x4  __attribute__((ext_vector_type(4)));

#define HW 4096
#define IMG_W 64

__device__ __forceinline__ float bfbits2f(unsigned short u) {
    return __uint_as_float(((unsigned int)u) << 16);
}
__device__ __forceinline__ short f2bs(float f) {
    bf16 h = __float2bfloat16(f);
    return *reinterpret_cast<short*>(&h);
}

// async global->LDS, 16B per lane. LDS dest = wave-uniform base + lane*16;
// the GLOBAL source address is per-lane (m173 pattern).
__device__ __forceinline__ void gl_lds16(const void* g, void* s) {
    __builtin_amdgcn_global_load_lds(
        (const __attribute__((address_space(1))) unsigned int*)g,
        (__attribute__((address_space(3))) unsigned int*)s, 16, 0, 0);
}

// ---------------------------------------------------------------------------
// pack_input: concat(gar,cond) fp32 [512][4096] -> inp_t bf16 chunked
// [cc=16][pix=4096][32ch] (conv1 DMA layout) AND gar_t bf16 pixel-major
// [4096 px][256 ch] (warp_combine gather layout).
// ---------------------------------------------------------------------------
__device__ void pack_input_dev(const float* __restrict__ gar,
                               const float* __restrict__ cond,
                               short* __restrict__ outp,
                               short* __restrict__ gart, int bx2, float* tile)
{
    int bx = bx2 & 127;                // px tile (128)
    int by = bx2 >> 7;                 // ch tile (16) == cc chunk
    int tx = threadIdx.x & 31;
    int ty = threadIdx.x >> 5;
#pragma unroll
    for (int i = 0; i < 4; ++i) {
        int c = by * 32 + ty + i * 8;
        const float* src = (c < 256) ? (gar + (size_t)c * HW)
                                     : (cond + (size_t)(c - 256) * HW);
        tile[(ty + i * 8) * 33 + tx] = src[bx * 32 + tx];
    }
    __syncthreads();
#pragma unroll
    for (int i = 0; i < 4; ++i) {
        int p = bx * 32 + ty + i * 8;
        short v = f2bs(tile[tx * 33 + ty + i * 8]);
        outp[((size_t)by * 4096 + p) * 32 + tx] = v;
        if (by < 8)                    // gar channels only (block-uniform)
            gart[(size_t)p * 256 + by * 32 + tx] = v;
    }
}

// ---------------------------------------------------------------------------
// pack_w: W fp32 [G][CREAL][CIN][3][3] -> bf16 blocks.
// COAL layout (all convs now): [g][nt][cc][tap 9][oc BN][q 4][8 ic] -> a
// wave's 64-lane weight-fragment load is one contiguous span; tap+1
// prefetch at tap 8 rolls into the next cc's tap 0 by construction.
// BLKB = 9*4*BN*16 bytes.
// ---------------------------------------------------------------------------
template<int CIN, int CREAL, int BN, int NT, bool COAL>
__device__ void pack_w_dev(const float* __restrict__ wgt, char* __restrict__ wp,
                           int bx, short* sT)
{
    constexpr int NCC  = CIN / 32;
    constexpr int BLKB = 9 * 4 * BN * 16;

    const int t  = threadIdx.x;
    const int cc = bx % NCC;
    const int nt = (bx / NCC) % NT;
    const int g  = bx / (NT * NCC);

    for (int i = t; i < BLKB / 8; i += 256)
        reinterpret_cast<s16x4*>(sT)[i] = s16x4{0, 0, 0, 0};
    __syncthreads();

    int ocmax = CREAL - nt * BN; if (ocmax > BN) ocmax = BN;
    const size_t base = ((size_t)(g * CREAL + nt * BN) * CIN + cc * 32) * 9;
    for (int i = t; i < ocmax * 288; i += 256) {
        int oc = i / 288;
        int r  = i % 288;                      // ic*9 + tap
        int ic = r / 9, tap = r % 9;
        size_t idx;
        if (COAL) idx = (size_t)(((tap * BN + oc) * 4 + (ic >> 3)) * 8 + (ic & 7));
        else      idx = (size_t)(((tap * 4 + (ic >> 3)) * BN + oc) * 8 + (ic & 7));
        sT[idx] = f2bs(wgt[base + (size_t)oc * CIN * 9 + r]);
    }
    __syncthreads();

    const s16x4* src = reinterpret_cast<const s16x4*>(sT);
    s16x4* dst = reinterpret_cast<s16x4*>(wp + (size_t)bx * BLKB);
    for (int i = t; i < BLKB / 8; i += 256)
        dst[i] = src[i];
}

// All packing in one launch (block-range dispatch; branch is block-uniform).
__global__ __launch_bounds__(256)
void pack_all(const float* __restrict__ gar, const float* __restrict__ cond,
              const float* __restrict__ W1, const float* __restrict__ W2,
              const float* __restrict__ W3, const float* __restrict__ W4,
              short* inp_t, short* gar_t,
              char* W1p, char* W2p, char* W3p, char* W4p)
{
    __shared__ __align__(16) short sbuf[9 * 4 * 64 * 8];   // 36864 B
    int bx = blockIdx.x;
    if (bx < 256)      pack_w_dev<512, 128, 64, 2, true>(W1, W1p, bx,       sbuf);
    else if (bx < 288) pack_w_dev<128,  64, 64, 1, true>(W2, W2p, bx - 256, sbuf);
    else if (bx < 304) pack_w_dev< 64,  32, 32, 1, true>(W3, W3p, bx - 288, sbuf);
    else if (bx < 312) pack_w_dev< 32,  18, 32, 1, true>(W4, W4p, bx - 304, sbuf);
    else pack_input_dev(gar, cond, inp_t, gar_t, bx - 312, (float*)sbuf);
}

// ---------------------------------------------------------------------------
// conv1_p2: dual-stream register pipeline, full-K. Round-6 verified
// structure (49.6-51.5us) with pixel-major [pix][128] epilogue.
// ---------------------------------------------------------------------------
__global__ __launch_bounds__(512, 2)
void conv1_p2(const short* __restrict__ inp, const char* __restrict__ wp,
              const float* __restrict__ bias, short* __restrict__ outp)
{
    __shared__ __align__(16) short sA[2][4][66][4][8];   // 33792 B

    const int b  = blockIdx.x;
    const int g  = b & 7;                     // XCD swizzle: group per XCD
    const int pt = b >> 3;                    // 0..31
    const int r0 = pt * 2;

    const int t    = threadIdx.x;
    const int wave = t >> 6, lane = t & 63;
    const int l15  = lane & 15, quad = lane >> 4;

    const int row_l = wave & 1;               // px row (0-1)
    const int ocq   = wave >> 1;              // oc quarter (0-3)
    const int ntw   = ocq >> 1;               // W1p nt half
    const int ocw64 = (ocq & 1) * 32;         // oc base within nt

    // W1p layout [g][nt][cc 16][tap 9][oc 64][q 4][ic 8]
    const short* wb    = (const short*)wp + (size_t)(g * 2 + ntw) * 16 * 18432;
    const short* wlane = wb + ((size_t)(ocw64 + l15) * 4 + quad) * 8;

    // staging: wave w -> halo row (w>>1), column half (w&1): 2 x 1KB DMA
    auto stageDMA = [&](int cc, int buf) {
        const int row = wave >> 1;
        const int gy  = r0 - 1 + row;
        if (gy >= 0 && gy < 64) {
            const short* src = inp + ((size_t)cc * 4096 + (size_t)gy * 64) * 32
                                   + (size_t)lane * 8;
            const int c4 = (wave & 1) * 2;
            gl_lds16(src + c4 * 512,       &sA[buf][row][1 + c4 * 16][0][0]);
            gl_lds16(src + (c4 + 1) * 512, &sA[buf][row][1 + (c4 + 1) * 16][0][0]);
        }
    };

    f32x4 acc[2][4];
#pragma unroll
    for (int o = 0; o < 2; ++o)
#pragma unroll
        for (int f = 0; f < 4; ++f)
#pragma unroll
            for (int r = 0; r < 4; ++r) acc[o][f][r] = 0.f;

    // prologue: DMA(0) into buf0, zero x-pads (both bufs) + OOB rows
    stageDMA(0, 0);
    if (t < 64) {
        int buf = t >> 5, row = (t >> 3) & 3, q = (t >> 1) & 3;
        int col = (t & 1) ? 65 : 0;
        *reinterpret_cast<bf16x8*>(&sA[buf][row][col][q][0]) =
            bf16x8{0, 0, 0, 0, 0, 0, 0, 0};
    }
    if (r0 == 0 || r0 == 62) {
        int zr = (r0 == 0) ? 0 : 3;           // gy=-1 or gy=64: zero forever
        for (int i = t; i < 2 * 66 * 4; i += 512) {
            int buf = i / 264, rem = i % 264;
            *reinterpret_cast<bf16x8*>(&sA[buf][zr][rem >> 2][rem & 3][0]) =
                bf16x8{0, 0, 0, 0, 0, 0, 0, 0};
        }
    }

    // weight double-buffer (16 VGPR) + pF double-buffer (32 VGPR)
    bf16x8 w[2][2];
    bf16x8 pf[2][4];
#pragma unroll
    for (int o = 0; o < 2; ++o)               // cc0 tap0 weights -> w[0]
        w[0][o] = *reinterpret_cast<const bf16x8*>(wlane + o * 512);

    auto body = [&](int cc, int cur, int par) {
        const short* wcc = wlane + (size_t)cc * 18432;
        __syncthreads();                      // sA[cur] published (DMA drained)
        if (cc + 1 < 16) stageDMA(cc + 1, cur ^ 1);
        // prime tap0 pF
#pragma unroll
        for (int f = 0; f < 4; ++f)
            pf[0][f] = *reinterpret_cast<const bf16x8*>(
                &sA[cur][row_l][f * 16 + l15][quad][0]);
#pragma unroll
        for (int tap = 0; tap < 9; ++tap) {
            const int pb = tap & 1, pn = pb ^ 1;
            const int cb = (tap + par) & 1, nb = cb ^ 1;
            // prefetch next tap's pF (taps 0-7)
            if (tap < 8) {
                const int dy1 = (tap + 1) / 3, dx1 = (tap + 1) % 3;
#pragma unroll
                for (int f = 0; f < 4; ++f)
                    pf[pn][f] = *reinterpret_cast<const bf16x8*>(
                        &sA[cur][row_l + dy1][f * 16 + l15 + dx1][quad][0]);
            }
            // prefetch next tap's weights (tap8 -> next cc's tap0 by layout)
            const short* nsrc = wcc + (size_t)(tap + 1) * 2048;
#pragma unroll
            for (int o = 0; o < 2; ++o)
                w[nb][o] = *reinterpret_cast<const bf16x8*>(nsrc + o * 512);
            __builtin_amdgcn_sched_barrier(0);   // pin both streams pre-MFMA
#pragma unroll
            for (int o = 0; o < 2; ++o)
#pragma unroll
                for (int f = 0; f < 4; ++f)
                    acc[o][f] = __builtin_amdgcn_mfma_f32_16x16x32_bf16(
                        w[cb][o], pf[pb][f], acc[o][f], 0, 0, 0);
        }
    };

    for (int c2 = 0; c2 < 16; c2 += 2) {
        body(c2,     0, 0);
        body(c2 + 1, 1, 1);
    }

    // epilogue: bias + leaky -> bf16, out [pix][128]. m(oc)=quad*4+reg.
    const int prow = r0 + row_l;
    const size_t pixbase = (size_t)g * 4096 + (size_t)prow * 64;
#pragma unroll
    for (int o = 0; o < 2; ++o)
#pragma unroll
        for (int reg = 0; reg < 4; ++reg) {
            const int ocg = ocq * 32 + o * 16 + quad * 4 + reg;
            const float bv = bias[g * 128 + ocg];
#pragma unroll
            for (int f = 0; f < 4; ++f) {
                float v = acc[o][f][reg] + bv;
                v = v >= 0.f ? v : 0.1f * v;
                outp[(pixbase + f * 16 + l15) * 128 + ocg] = f2bs(v);
            }
        }
}

// ---------------------------------------------------------------------------
// conv2_p2: conv1_p2 structure for conv2 (128->64). NCC=4, OF=1 (8 waves =
// 2 px-rows x 4 oc-16-groups). Input: hid1 pixel-major [g*4096+pix][128],
// staged via per-lane gl_lds16 source addresses. Output: hid2 pixel-major
// [pix][64]. Grid 256 x 512 thr. (round-8 verified)
// ---------------------------------------------------------------------------
__global__ __launch_bounds__(512, 2)
void conv2_p2(const short* __restrict__ inp, const char* __restrict__ wp,
              const float* __restrict__ bias, short* __restrict__ outp)
{
    __shared__ __align__(16) short sA[2][4][66][4][8];   // 33792 B

    const int b  = blockIdx.x;
    const int g  = b & 7;
    const int pt = b >> 3;                    // 0..31
    const int r0 = pt * 2;

    const int t    = threadIdx.x;
    const int wave = t >> 6, lane = t & 63;
    const int l15  = lane & 15, quad = lane >> 4;

    const int row_l = wave & 1;               // px row (0-1)
    const int ocq   = wave >> 1;              // oc 16-group (0-3)

    // W2p layout [g][cc 4][tap 9][oc 64][q 4][ic 8]
    const short* wb    = (const short*)wp + (size_t)g * 4 * 18432;
    const short* wlane = wb + ((size_t)(ocq * 16 + l15) * 4 + quad) * 8;

    auto stageDMA = [&](int cc, int buf) {
        const int row = wave >> 1;
        const int gy  = r0 - 1 + row;
        if (gy >= 0 && gy < 64) {
            const short* rowb = inp + ((size_t)g * 4096 + (size_t)gy * 64) * 128
                                    + cc * 32 + (lane & 3) * 8;
            const int c4 = (wave & 1) * 2;
            gl_lds16(rowb + (size_t)(c4 * 16 + (lane >> 2)) * 128,
                     &sA[buf][row][1 + c4 * 16][0][0]);
            gl_lds16(rowb + (size_t)((c4 + 1) * 16 + (lane >> 2)) * 128,
                     &sA[buf][row][1 + (c4 + 1) * 16][0][0]);
        }
    };

    f32x4 acc[4];
#pragma unroll
    for (int f = 0; f < 4; ++f)
#pragma unroll
        for (int r = 0; r < 4; ++r) acc[f][r] = 0.f;

    stageDMA(0, 0);
    if (t < 64) {
        int buf = t >> 5, row = (t >> 3) & 3, q = (t >> 1) & 3;
        int col = (t & 1) ? 65 : 0;
        *reinterpret_cast<bf16x8*>(&sA[buf][row][col][q][0]) =
            bf16x8{0, 0, 0, 0, 0, 0, 0, 0};
    }
    if (r0 == 0 || r0 == 62) {
        int zr = (r0 == 0) ? 0 : 3;
        for (int i = t; i < 2 * 66 * 4; i += 512) {
            int buf = i / 264, rem = i % 264;
            *reinterpret_cast<bf16x8*>(&sA[buf][zr][rem >> 2][rem & 3][0]) =
                bf16x8{0, 0, 0, 0, 0, 0, 0, 0};
        }
    }

    bf16x8 w[2];
    bf16x8 pf[2][4];
    w[0] = *reinterpret_cast<const bf16x8*>(wlane);

    auto body = [&](int cc, int cur, int par) {
        const short* wcc = wlane + (size_t)cc * 18432;
        __syncthreads();
        if (cc + 1 < 4) stageDMA(cc + 1, cur ^ 1);
#pragma unroll
        for (int f = 0; f < 4; ++f)
            pf[0][f] = *reinterpret_cast<const bf16x8*>(
                &sA[cur][row_l][f * 16 + l15][quad][0]);
#pragma unroll
        for (int tap = 0; tap < 9; ++tap) {
            const int pb = tap & 1, pn = pb ^ 1;
            const int cb = (tap + par) & 1, nb = cb ^ 1;
            if (tap < 8) {
                const int dy1 = (tap + 1) / 3, dx1 = (tap + 1) % 3;
#pragma unroll
                for (int f = 0; f < 4; ++f)
                    pf[pn][f] = *reinterpret_cast<const bf16x8*>(
                        &sA[cur][row_l + dy1][f * 16 + l15 + dx1][quad][0]);
            }
            w[nb] = *reinterpret_cast<const bf16x8*>(
                wcc + (size_t)(tap + 1) * 2048);
            __builtin_amdgcn_sched_barrier(0);
#pragma unroll
            for (int f = 0; f < 4; ++f)
                acc[f] = __builtin_amdgcn_mfma_f32_16x16x32_bf16(
                    w[cb], pf[pb][f], acc[f], 0, 0, 0);
        }
    };

    for (int c2 = 0; c2 < 4; c2 += 2) {
        body(c2,     0, 0);
        body(c2 + 1, 1, 1);
    }

    // epilogue: bias + leaky -> bf16, hid2 pixel-major [g*4096+pix][64].
    const int prow = r0 + row_l;
    const size_t pixbase = (size_t)g * 4096 + (size_t)prow * 64;
#pragma unroll
    for (int reg = 0; reg < 4; ++reg) {
        const int ocg = ocq * 16 + quad * 4 + reg;
        const float bv = bias[g * 64 + ocg];
#pragma unroll
        for (int f = 0; f < 4; ++f) {
            float v = acc[f][reg] + bv;
            v = v >= 0.f ? v : 0.1f * v;
            outp[(pixbase + f * 16 + l15) * 64 + ocg] = f2bs(v);
        }
    }
}

// ---------------------------------------------------------------------------
// conv34_p2: FUSED conv3 (64->32, leaky) + conv4 (32->18 pad 32, linear).
// Rationale: the two old-template kernels ran at 1 block/CU, 4 waves/CU,
// latency-dominated (~3us/cc barrier floor) for <2 GFLOP total, plus a
// 1.3 MB hid3 HBM round-trip. Fusing removes one dispatch, one kernel's
// fixed cost, and keeps hid3 entirely in LDS.
// Per block (grid 256 = 32 pt x 8 g, 512 thr):
//   stage 6 halo rows of hid2 (48 KB, per-lane DMA, pixel-major source)
//   conv3: wave = hid3row(0-3) x ochalf(0-1); 2cc x 9tap x P4 = 72 MFMA,
//          dual-stream reg pipeline; bias3+leaky -> bf16 -> sH3 (LDS),
//          OOB hid3 rows written as zeros
//   barrier
//   conv4: wave = outrow(0-1) x ochalf(0-1) x pxhalf(0-1); 9tap x P2 =
//          18 MFMA; bias4 (no leaky) -> oa fp32 [g*18+oc][4096]
// LDS: sA 50688 + sH3 16896 = 67.5 KB.
// ---------------------------------------------------------------------------
__global__ __launch_bounds__(512, 2)
void conv34_p2(const short* __restrict__ hid2, const char* __restrict__ w3p,
               const char* __restrict__ w4p, const float* __restrict__ b3,
               const float* __restrict__ b4, float* __restrict__ oa)
{
    __shared__ __align__(16) short sA[6][2][66][4][8];   // 50688 B
    __shared__ __align__(16) short sH3[4][66][4][8];     // 16896 B

    const int b  = blockIdx.x;
    const int g  = b & 7;                     // XCD swizzle
    const int pt = b >> 3;                    // 0..31
    const int r0 = pt * 2;

    const int t    = threadIdx.x;
    const int wave = t >> 6, lane = t & 63;
    const int l15  = lane & 15, quad = lane >> 4;

    // conv3 mapping: hid3 row (0-3) x oc-half (0-1)
    const int wrow = wave & 3;
    const int och3 = wave >> 2;
    // conv4 mapping: out row (0-1) x oc-half (0-1) x px-half (0-1)
    const int w4row = wave & 1;
    const int och4  = (wave >> 1) & 1;
    const int pxh   = wave >> 2;

    // W3p [g][cc2][tap9][oc32][q4][ic8] (9216 shorts/block);
    // W4p [g][tap9][oc32][q4][ic8]
    const short* w3lane = (const short*)w3p + (size_t)(g * 2) * 9216
                        + ((size_t)(och3 * 16 + l15) * 4 + quad) * 8;
    const short* w4lane = (const short*)w4p + (size_t)g * 9216
                        + ((size_t)(och4 * 16 + l15) * 4 + quad) * 8;

    // ---- stage hid2 rows r0-2 .. r0+3 (waves 0-5; row = wave) ----
    if (wave < 6) {
        const int gy = r0 - 2 + wave;
        if (gy >= 0 && gy < 64) {
            const short* src = hid2 + ((size_t)g * 4096 + (size_t)gy * 64) * 64;
#pragma unroll
            for (int cc = 0; cc < 2; ++cc)
#pragma unroll
                for (int i = 0; i < 4; ++i)
                    gl_lds16(src + (size_t)(i * 16 + (lane >> 2)) * 64
                                 + cc * 32 + (lane & 3) * 8,
                             &sA[wave][cc][1 + i * 16][0][0]);
        } else {
            s16x4* rowdst = reinterpret_cast<s16x4*>(&sA[wave][0][0][0][0]);
            for (int i = lane; i < 1056; i += 64)
                rowdst[i] = s16x4{0, 0, 0, 0};
        }
    }
    // zero x-pad cols: sA (6r x 2cc x {0,65} x 4q = 96) + sH3 (4 x 2 x 4 = 32)
    if (t < 96) {
        int row = t / 16, cc = (t >> 3) & 1, col = (t & 4) ? 65 : 0, q = t & 3;
        *reinterpret_cast<bf16x8*>(&sA[row][cc][col][q][0]) =
            bf16x8{0, 0, 0, 0, 0, 0, 0, 0};
    } else if (t < 128) {
        int i = t - 96;
        int row = i >> 3, col = (i & 4) ? 65 : 0, q = i & 3;
        *reinterpret_cast<bf16x8*>(&sH3[row][col][q][0]) =
            bf16x8{0, 0, 0, 0, 0, 0, 0, 0};
    }

    // ---- conv3 ----
    bf16x8 w[2];
    bf16x8 pf[2][4];
    w[0] = *reinterpret_cast<const bf16x8*>(w3lane);   // cc0 tap0

    f32x4 acc3[4];
#pragma unroll
    for (int f = 0; f < 4; ++f)
#pragma unroll
        for (int r = 0; r < 4; ++r) acc3[f][r] = 0.f;

    __syncthreads();                          // staging + pads visible

#pragma unroll
    for (int cc = 0; cc < 2; ++cc) {
        const short* wcc = w3lane + (size_t)cc * 9216;
#pragma unroll
        for (int f = 0; f < 4; ++f)
            pf[0][f] = *reinterpret_cast<const bf16x8*>(
                &sA[wrow][cc][f * 16 + l15][quad][0]);
#pragma unroll
        for (int tap = 0; tap < 9; ++tap) {
            const int pb = tap & 1, pn = pb ^ 1;
            const int cb = (tap + cc) & 1, nb = cb ^ 1;
            if (tap < 8) {
                const int dy1 = (tap + 1) / 3, dx1 = (tap + 1) % 3;
#pragma unroll
                for (int f = 0; f < 4; ++f)
                    pf[pn][f] = *reinterpret_cast<const bf16x8*>(
                        &sA[wrow + dy1][cc][f * 16 + l15 + dx1][quad][0]);
            }
            // tap8 -> next cc's tap0 (block stride == 9*1024 shorts);
            // final overread lands in dead workspace before W4p.
            w[nb] = *reinterpret_cast<const bf16x8*>(
                wcc + (size_t)(tap + 1) * 1024);
            __builtin_amdgcn_sched_barrier(0);
#pragma unroll
            for (int f = 0; f < 4; ++f)
                acc3[f] = __builtin_amdgcn_mfma_f32_16x16x32_bf16(
                    w[cb], pf[pb][f], acc3[f], 0, 0, 0);
        }
    }

    // hid3 -> sH3 (bias3 + leaky, bf16). OOB hid3 rows = zeros.
    {
        const int gy3 = r0 - 1 + wrow;
        const bool v3 = (gy3 >= 0 && gy3 < 64);
        const int qp = och3 * 2 + (quad >> 1);
        const int e0 = (quad & 1) * 4;
#pragma unroll
        for (int f = 0; f < 4; ++f) {
            s16x4 pkt;
#pragma unroll
            for (int reg = 0; reg < 4; ++reg) {
                const int oc3 = och3 * 16 + quad * 4 + reg;
                float v = acc3[f][reg] + b3[g * 32 + oc3];
                v = v >= 0.f ? v : 0.1f * v;
                pkt[reg] = v3 ? f2bs(v) : (short)0;
            }
            *reinterpret_cast<s16x4*>(&sH3[wrow][1 + f * 16 + l15][qp][e0]) = pkt;
        }
    }
    __syncthreads();                          // sH3 complete

    // ---- conv4 ----
    bf16x8 w4[2];
    bf16x8 pf4[2][2];
    w4[0] = *reinterpret_cast<const bf16x8*>(w4lane);

    f32x4 acc4[2];
#pragma unroll
    for (int f = 0; f < 2; ++f)
#pragma unroll
        for (int r = 0; r < 4; ++r) acc4[f][r] = 0.f;

#pragma unroll
    for (int f = 0; f < 2; ++f)
        pf4[0][f] = *reinterpret_cast<const bf16x8*>(
            &sH3[w4row][pxh * 32 + f * 16 + l15][quad][0]);
#pragma unroll
    for (int tap = 0; tap < 9; ++tap) {
        const int pb = tap & 1, pn = pb ^ 1;
        const int cb = tap & 1, nb = cb ^ 1;
        if (tap < 8) {
            const int dy1 = (tap + 1) / 3, dx1 = (tap + 1) % 3;
#pragma unroll
            for (int f = 0; f < 2; ++f)
                pf4[pn][f] = *reinterpret_cast<const bf16x8*>(
                    &sH3[w4row + dy1][pxh * 32 + f * 16 + l15 + dx1][quad][0]);
        }
        // tap8 overread: next g's block / dead workspace. harmless.
        w4[nb] = *reinterpret_cast<const bf16x8*>(
            w4lane + (size_t)(tap + 1) * 1024);
        __builtin_amdgcn_sched_barrier(0);
#pragma unroll
        for (int f = 0; f < 2; ++f)
            acc4[f] = __builtin_amdgcn_mfma_f32_16x16x32_bf16(
                w4[cb], pf4[pb][f], acc4[f], 0, 0, 0);
    }

    // epilogue: bias4 (no leaky) -> oa fp32 [(g*18+oc)][4096]
    const int prow4 = r0 + w4row;
#pragma unroll
    for (int reg = 0; reg < 4; ++reg) {
        const int oc4 = och4 * 16 + quad * 4 + reg;
        if (oc4 < 18) {
            const float bv = b4[g * 18 + oc4];
#pragma unroll
            for (int f = 0; f < 2; ++f)
                oa[(size_t)(g * 18 + oc4) * HW + prow4 * 64 + pxh * 32
                   + f * 16 + l15] = acc4[f][reg] + bv;
        }
    }
}

// ---------------------------------------------------------------------------
// Fused softmax-over-groups + bilinear params + warp + combine (fp32 out).
// gar channels from gar_t pixel-major [4096][256]: one gather = 512 B
// contiguous per 32-lane group (4x128B lines).
// ---------------------------------------------------------------------------
__global__ __launch_bounds__(256)
void warp_combine_kernel(const float* __restrict__ oa,
                         const short* __restrict__ gar_t,
                         const float* __restrict__ mask,
                         float* __restrict__ out)
{
    __shared__ __align__(16) float4 sWts[8][6][8];
    __shared__ __align__(16) int4   sIdx[8][6][8];

    const int t = threadIdx.x;

    if (t < 48) {
        int lp = t / 6;
        int k  = t % 6;
        int p  = blockIdx.x * 8 + lp;
        int x  = p & 63, y = p >> 6;

        float l[8];
        float m = -1e30f;
#pragma unroll
        for (int g = 0; g < 8; ++g) {
            l[g] = oa[(size_t)(g * 18 + 12 + k) * HW + p];
            m = fmaxf(m, l[g]);
        }
        float s = 0.f;
#pragma unroll
        for (int g = 0; g < 8; ++g) { l[g] = __expf(l[g] - m); s += l[g]; }
        float inv = 1.f / s;

#pragma unroll
        for (int g = 0; g < 8; ++g) {
            float a  = l[g] * inv;
            float ox = oa[(size_t)(g * 18 + 2 * k)     * HW + p];
            float oy = oa[(size_t)(g * 18 + 2 * k + 1) * HW + p];
            float sx = fminf(fmaxf(((float)x + ox) * (64.f / 63.f) - 0.5f, 0.f), 63.f);
            float sy = fminf(fmaxf(((float)y + oy) * (64.f / 63.f) - 0.5f, 0.f), 63.f);
            float fx0 = floorf(sx), fy0 = floorf(sy);
            int   x0 = (int)fx0,    y0i = (int)fy0;
            float wx = sx - fx0,    wy = sy - fy0;
            int   x1 = min(x0 + 1, 63), y1 = min(y0i + 1, 63);
            sWts[lp][k][g] = make_float4(a * (1.f - wy) * (1.f - wx),
                                         a * (1.f - wy) * wx,
                                         a * wy * (1.f - wx),
                                         a * wy * wx);
            sIdx[lp][k][g] = make_int4(y0i * 64 + x0, y0i * 64 + x1,
                                       y1  * 64 + x0, y1  * 64 + x1);
        }
    }
    __syncthreads();

    const int lp = t >> 5;
    const int p  = blockIdx.x * 8 + lp;
    const int c0 = (t & 31) * 8;
    const short* ipc = gar_t + c0;            // pixel-major: row stride 256

    float acc[8];
#pragma unroll
    for (int j = 0; j < 8; ++j) acc[j] = 0.f;

    for (int g = 0; g < 8; ++g) {
        float4 m0 = *reinterpret_cast<const float4*>(mask + g * 256 + c0);
        float4 m1 = *reinterpret_cast<const float4*>(mask + g * 256 + c0 + 4);
        float mk[8] = {m0.x, m0.y, m0.z, m0.w, m1.x, m1.y, m1.z, m1.w};
#pragma unroll
        for (int k = 0; k < 6; ++k) {
            float4 w  = sWts[lp][k][g];
            int4   id = sIdx[lp][k][g];
            ushort8v v00 = *reinterpret_cast<const ushort8v*>(ipc + (size_t)id.x * 256);
            ushort8v v01 = *reinterpret_cast<const ushort8v*>(ipc + (size_t)id.y * 256);
            ushort8v v10 = *reinterpret_cast<const ushort8v*>(ipc + (size_t)id.z * 256);
            ushort8v v11 = *reinterpret_cast<const ushort8v*>(ipc + (size_t)id.w * 256);
#pragma unroll
            for (int j = 0; j < 8; ++j) {
                float sv = w.x * bfbits2f(v00[j]) + w.y * bfbits2f(v01[j])
                         + w.z * bfbits2f(v10[j]) + w.w * bfbits2f(v11[j]);
                acc[j] = fmaf(mk[j], sv, acc[j]);
            }
        }
    }
#pragma unroll
    for (int j = 0; j < 8; ++j)
        out[(size_t)(c0 + j) * HW + p] = acc[j];
}

// ---------------------------------------------------------------------------
// Workspace (~28 MB): inp_t 0-4M | W1p 4-9.2M (hid2 overlays dead W1p) |
// oa 10.5-12.9M | W2p 14M | W3p 15.5M | W4p 16M | hid1 17-25M |
// gar_t 26-28M. (hid3 eliminated by conv34 fusion.)
// ---------------------------------------------------------------------------
extern "C" void kernel_launch(void* const* d_in, const int* in_sizes, int n_in,
                              void* d_out, int out_size, void* d_ws, size_t ws_size,
                              hipStream_t stream)
{
    (void)in_sizes; (void)n_in; (void)out_size; (void)ws_size;
    const float* gar  = (const float*)d_in[0];
    const float* cond = (const float*)d_in[1];
    const float* mask = (const float*)d_in[2];
    const float* W1   = (const float*)d_in[3];
    const float* b1   = (const float*)d_in[4];
    const float* W2   = (const float*)d_in[5];
    const float* b2   = (const float*)d_in[6];
    const float* W3   = (const float*)d_in[7];
    const float* b3   = (const float*)d_in[8];
    const float* W4   = (const float*)d_in[9];
    const float* b4   = (const float*)d_in[10];
    float* out = (float*)d_out;

    char* ws = (char*)d_ws;
    short* inp_t  = (short*)(ws);
    char*  W1p    = ws + (4u << 20);
    short* hid2_t = (short*)(ws + (4u << 20));          // overlays dead W1p
    float* oa     = (float*)(ws + (10u << 20) + (512u << 10));
    char*  W2p    = ws + (14u << 20);
    char*  W3p    = ws + (15u << 20) + (512u << 10);
    char*  W4p    = ws + (16u << 20);
    short* hid1_t = (short*)(ws + (17u << 20));
    short* gar_t  = (short*)(ws + (26u << 20));

    // 312 weight-pack blocks + 2048 input-transpose blocks, one launch
    pack_all<<<2360, 256, 0, stream>>>(gar, cond, W1, W2, W3, W4,
                                       inp_t, gar_t, W1p, W2p, W3p, W4p);

    // conv1: round-6 verified kernel (pixel-major out)
    conv1_p2<<<256, 512, 0, stream>>>(inp_t, W1p, b1, hid1_t);
    // conv2: conv1_p2-style, per-lane DMA staging from pixel-major hid1
    conv2_p2<<<256, 512, 0, stream>>>(hid1_t, W2p, b2, hid2_t);
    // conv3+conv4 FUSED: hid3 stays in LDS; one dispatch fewer
    conv34_p2<<<256, 512, 0, stream>>>(hid2_t, W3p, W4p, b3, b4, oa);

    warp_combine_kernel<<<512, 256, 0, stream>>>(oa, gar_t, mask, out);
}